// Round 1
// baseline (6506.727 us; speedup 1.0000x reference)
//
#include <hip/hip_runtime.h>

#define B_   64
#define T_   512
#define D_   512
#define H_   1024
#define G4   4096      // 4*H
#define KC_N 48        // (D+H)/32 k-chunks
#define NBLK_HALF 128  // blocks per batch-half barrier

typedef float f32x4 __attribute__((ext_vector_type(4)));
typedef short s16x8 __attribute__((ext_vector_type(8)));

__device__ __forceinline__ unsigned short f2bf(float f) {
    unsigned int u = __float_as_uint(f);
    u = (u + 0x7fffu + ((u >> 16) & 1u)) >> 16;   // RNE
    return (unsigned short)u;
}
__device__ __forceinline__ float sigm(float x) { return 1.f / (1.f + __expf(-x)); }
__device__ __forceinline__ float tanh_f(float x) { return 1.f - 2.f / (__expf(2.f * x) + 1.f); }

// 8x f32 -> 8x bf16 (RNE) via v_cvt_pk_bf16_f32 (lo = src0)
__device__ __forceinline__ s16x8 cvt8(float4 a, float4 b) {
    union { s16x8 v; unsigned int u[4]; } r;
    asm("v_cvt_pk_bf16_f32 %0, %1, %2" : "=v"(r.u[0]) : "v"(a.x), "v"(a.y));
    asm("v_cvt_pk_bf16_f32 %0, %1, %2" : "=v"(r.u[1]) : "v"(a.z), "v"(a.w));
    asm("v_cvt_pk_bf16_f32 %0, %1, %2" : "=v"(r.u[2]) : "v"(b.x), "v"(b.y));
    asm("v_cvt_pk_bf16_f32 %0, %1, %2" : "=v"(r.u[3]) : "v"(b.z), "v"(b.w));
    return r.v;
}

// Pack [W_ih | W_hh] into exact MFMA B-fragment order, bf16, gate-interleaved
// columns (packed col n = 4*j_hidden + gate). Unchanged from previous version:
// Wpk[(((c*48 + kc)*64 + lane))*8 + j] = W[row(n)][k], n = c*16 + (lane&15),
// k = kc*32 + (lane>>4)*8 + j.
__global__ __launch_bounds__(256) void pack_w(const float* __restrict__ W_ih,
                                              const float* __restrict__ W_hh,
                                              unsigned short* __restrict__ Wpk) {
    int tid = blockIdx.x * 256 + threadIdx.x;        // [0, 256*48*64*8)
    int j    = tid & 7;
    int lane = (tid >> 3) & 63;
    int rest = tid >> 9;
    int kc = rest % KC_N;
    int c  = rest / KC_N;
    int npk = c * 16 + (lane & 15);
    int jh = npk >> 2, g = npk & 3;
    int row = g * H_ + jh;                           // torch gate order i,f,g,o
    int k = kc * 32 + (lane >> 4) * 8 + j;
    float v = (k < D_) ? W_ih[row * D_ + k] : W_hh[row * H_ + (k - D_)];
    Wpk[tid] = f2bf(v);
}

__global__ __launch_bounds__(256) void init_state2(
    const float* __restrict__ h0, const float* __restrict__ b_ih,
    const float* __restrict__ b_hh, unsigned short* __restrict__ hbuf,
    float* __restrict__ bias_p, unsigned int* __restrict__ bar)
{
    int tid = blockIdx.x * 256 + threadIdx.x;        // 65536 threads
    int j = tid & (H_ - 1);
    hbuf[tid] = f2bf(h0[j]);                         // h buffer 0: [64][1024] bf16
    if (tid < G4) {                                  // bias in packed-col order
        int jh = tid >> 2, g = tid & 3;
        bias_p[tid] = b_ih[g * H_ + jh] + b_hh[g * H_ + jh];
    }
    if (tid < 64) bar[tid] = 0u;                     // two barrier counters (+padding)
}

// Persistent LSTM: one launch, 256 blocks (1/CU), 512 threads (8 waves).
// block = (colgroup cg of 32 packed cols = 8 hidden units) x (batch half mh of 32 rows)
// wave  = (mi in 0..1: 16-row m-tile) x (ks in 0..3: 384-wide k-slice)
// Weights: persistent VGPR B-fragments (24 x s16x8 per wave = 96 VGPR).
// h: double-buffered global bf16, exchanged via agent-scope (sc1) atomics.
// c,h state: registers of epilogue threads. Barrier: monotonic counter per half.
__global__ __launch_bounds__(512, 2) void lstm_persist(
    const float* __restrict__ x, const int* __restrict__ mask,
    const unsigned short* __restrict__ Wpk, const float* __restrict__ bias_p,
    const float* __restrict__ h0, const float* __restrict__ c0,
    unsigned short* __restrict__ hbuf, float* __restrict__ out,
    unsigned int* __restrict__ bar)
{
    const int tid = threadIdx.x;
    const int bid = blockIdx.x;
    const int cg  = bid >> 1;            // 0..127 colgroup (32 packed cols)
    const int mh  = bid & 1;             // batch half
    const int b0g = mh << 5;             // batch row base

    const int w = tid >> 6, l = tid & 63;
    const int quad = l >> 4, l15 = l & 15;
    const int mi = w >> 2;               // 0..1
    const int ks = w & 3;                // 0..3
    const int arow = b0g + mi * 16 + l15;

    __shared__ float Dls[4][32][36];     // [ks][m-row][gate-col], padded

    // ---- persistent B fragments: 2 ntiles x 12 kc, fully unrolled (static idx) ----
    s16x8 Bf0[12], Bf1[12];
    #pragma unroll
    for (int i = 0; i < 12; ++i) {
        int kc = ks * 12 + i;
        Bf0[i] = *reinterpret_cast<const s16x8*>(Wpk + (size_t)(((cg * 2 + 0) * KC_N + kc) * 64 + l) * 8);
        Bf1[i] = *reinterpret_cast<const s16x8*>(Wpk + (size_t)(((cg * 2 + 1) * KC_N + kc) * 64 + l) * 8);
    }

    // ---- epilogue thread state (tid<256): thread -> (batch b_l, hidden unit u) ----
    const int b_l = tid >> 3, u = tid & 7;
    const int brow = b0g + b_l;
    const int jcol = cg * 8 + u;
    float c_reg = 0.f, h_reg = 0.f;
    float4 bias = make_float4(0.f, 0.f, 0.f, 0.f);
    if (tid < 256) {
        c_reg = c0[jcol];                // c0/h0 are (1,H) broadcasts
        h_reg = h0[jcol];
        bias = *reinterpret_cast<const float4*>(bias_p + cg * 32 + u * 4);
    }

    unsigned int* cnt = bar + mh * 32;   // separate cacheline per batch half

    #pragma unroll 1
    for (int t = 0; t < T_; ++t) {
        const unsigned short* hin  = hbuf + (size_t)(t & 1) * (B_ * H_);
        unsigned short*       hout = hbuf + (size_t)((t + 1) & 1) * (B_ * H_);

        // ---- GEMM phase: gates[m-tile][32 cols] partial over this k-slice ----
        f32x4 a0 = {0.f, 0.f, 0.f, 0.f}, a1 = {0.f, 0.f, 0.f, 0.f};
        const float* xrow = x + ((size_t)arow * T_ + t) * D_;
        #pragma unroll
        for (int i = 0; i < 12; ++i) {
            int kc = ks * 12 + i;
            s16x8 af;
            if (kc < 16) {               // x part: f32 -> bf16 (L2-cached, never inv'd)
                const float* xp = xrow + kc * 32 + quad * 8;
                float4 v0 = *reinterpret_cast<const float4*>(xp);
                float4 v1 = *reinterpret_cast<const float4*>(xp + 4);
                af = cvt8(v0, v1);
            } else {                     // h part: coherent (sc1) loads from LLC
                const unsigned int* hp = reinterpret_cast<const unsigned int*>(
                    hin + (size_t)arow * H_ + (kc - 16) * 32 + quad * 8);
                union { s16x8 v; unsigned int u4[4]; } au;
                au.u4[0] = __hip_atomic_load(hp + 0, __ATOMIC_RELAXED, __HIP_MEMORY_SCOPE_AGENT);
                au.u4[1] = __hip_atomic_load(hp + 1, __ATOMIC_RELAXED, __HIP_MEMORY_SCOPE_AGENT);
                au.u4[2] = __hip_atomic_load(hp + 2, __ATOMIC_RELAXED, __HIP_MEMORY_SCOPE_AGENT);
                au.u4[3] = __hip_atomic_load(hp + 3, __ATOMIC_RELAXED, __HIP_MEMORY_SCOPE_AGENT);
                af = au.v;
            }
            a0 = __builtin_amdgcn_mfma_f32_16x16x32_bf16(af, Bf0[i], a0, 0, 0, 0);
            a1 = __builtin_amdgcn_mfma_f32_16x16x32_bf16(af, Bf1[i], a1, 0, 0, 0);
        }
        // C/D layout: col = lane&15, row = quad*4 + reg (m89-verified, as before)
        #pragma unroll
        for (int r = 0; r < 4; ++r) {
            Dls[ks][mi * 16 + quad * 4 + r][l15]      = a0[r];
            Dls[ks][mi * 16 + quad * 4 + r][16 + l15] = a1[r];
        }
        __syncthreads();

        // ---- epilogue: reduce 4 k-slices, LSTM cell update, h/out stores ----
        if (tid < 256) {
            f32x4 s0 = *reinterpret_cast<f32x4*>(&Dls[0][b_l][u * 4]);
            f32x4 s1 = *reinterpret_cast<f32x4*>(&Dls[1][b_l][u * 4]);
            f32x4 s2 = *reinterpret_cast<f32x4*>(&Dls[2][b_l][u * 4]);
            f32x4 s3 = *reinterpret_cast<f32x4*>(&Dls[3][b_l][u * 4]);
            f32x4 g = s0 + s1 + s2 + s3;
            float gi = sigm  (g[0] + bias.x);
            float gf = sigm  (g[1] + bias.y);
            float gg = tanh_f(g[2] + bias.z);
            float go = sigm  (g[3] + bias.w);
            float c_new = gf * c_reg + gi * gg;
            float h_new = go * tanh_f(c_new);
            int m = mask[(size_t)brow * T_ + t];
            float h2 = m ? h_new : h_reg;
            c_reg = m ? c_new : c_reg;
            h_reg = h2;
            out[((size_t)brow * T_ + t) * H_ + jcol] = h2;
            // pair adjacent units into one dword, store coherently (sc1)
            unsigned int hv = (unsigned int)f2bf(h2);
            unsigned int hx = (unsigned int)__shfl_xor((int)hv, 1);
            if ((u & 1) == 0) {
                unsigned int pk = (hx << 16) | hv;
                __hip_atomic_store(reinterpret_cast<unsigned int*>(hout + (size_t)brow * H_ + jcol),
                                   pk, __ATOMIC_RELAXED, __HIP_MEMORY_SCOPE_AGENT);
            }
        }
        __syncthreads();   // drains vmcnt: all waves' h-stores acknowledged at LLC

        // ---- device-scope barrier (per batch half; skipped after last step) ----
        if (t < T_ - 1) {
            if (tid == 0) {
                __hip_atomic_fetch_add(cnt, 1u, __ATOMIC_RELAXED, __HIP_MEMORY_SCOPE_AGENT);
                const unsigned int target = (unsigned int)(t + 1) * NBLK_HALF;
                int guard = 0;
                while (__hip_atomic_load(cnt, __ATOMIC_RELAXED, __HIP_MEMORY_SCOPE_AGENT) < target) {
                    __builtin_amdgcn_s_sleep(2);
                    if (++guard > (1 << 20)) break;   // safety valve: never hang
                }
            }
            __builtin_amdgcn_fence(__ATOMIC_ACQUIRE, "workgroup"); // compiler ordering, no L2 inv
            __syncthreads();
        }
    }
}

extern "C" void kernel_launch(void* const* d_in, const int* in_sizes, int n_in,
                              void* d_out, int out_size, void* d_ws, size_t ws_size,
                              hipStream_t stream)
{
    const float* x    = (const float*)d_in[0];
    const int*   mask = (const int*)d_in[1];
    const float* W_ih = (const float*)d_in[2];
    const float* W_hh = (const float*)d_in[3];
    const float* b_ih = (const float*)d_in[4];
    const float* b_hh = (const float*)d_in[5];
    const float* h0   = (const float*)d_in[6];
    const float* c0   = (const float*)d_in[7];
    float* out = (float*)d_out;

    // ws layout (~12.9 MB total)
    char* wsb = (char*)d_ws;
    unsigned short* Wpk    = (unsigned short*)(wsb);             // 12,582,912 B
    float*          bias_p = (float*)(wsb + 12582912);           //     16,384 B
    unsigned short* hbuf   = (unsigned short*)(wsb + 12599296);  //    262,144 B (2 buffers)
    unsigned int*   bar    = (unsigned int*)(wsb + 12861440);    //        256 B

    // inputs re-poisoned every call -> re-pack every call
    pack_w<<<24576, 256, 0, stream>>>(W_ih, W_hh, Wpk);
    init_state2<<<256, 256, 0, stream>>>(h0, b_ih, b_hh, hbuf, bias_p, bar);
    lstm_persist<<<256, 512, 0, stream>>>(x, mask, Wpk, bias_p, h0, c0, hbuf, out, bar);
}

// Round 3
// 3749.183 us; speedup vs baseline: 1.7355x; 1.7355x over previous
//
#include <hip/hip_runtime.h>

#define B_   64
#define T_   512
#define D_   512
#define H_   1024
#define G4   4096      // 4*H
#define KC_N 48        // (D+H)/32 k-chunks

typedef float f32x4 __attribute__((ext_vector_type(4)));
typedef short s16x8 __attribute__((ext_vector_type(8)));

__device__ __forceinline__ unsigned short f2bf(float f) {
    unsigned int u = __float_as_uint(f);
    u = (u + 0x7fffu + ((u >> 16) & 1u)) >> 16;   // RNE
    return (unsigned short)u;
}
__device__ __forceinline__ float sigm(float x) { return 1.f / (1.f + __expf(-x)); }
__device__ __forceinline__ float tanh_f(float x) { return 1.f - 2.f / (__expf(2.f * x) + 1.f); }

// 8x f32 -> 8x bf16 (RNE) via v_cvt_pk_bf16_f32 (lo = src0)
__device__ __forceinline__ s16x8 cvt8(float4 a, float4 b) {
    union { s16x8 v; unsigned int u[4]; } r;
    asm("v_cvt_pk_bf16_f32 %0, %1, %2" : "=v"(r.u[0]) : "v"(a.x), "v"(a.y));
    asm("v_cvt_pk_bf16_f32 %0, %1, %2" : "=v"(r.u[1]) : "v"(a.z), "v"(a.w));
    asm("v_cvt_pk_bf16_f32 %0, %1, %2" : "=v"(r.u[2]) : "v"(b.x), "v"(b.y));
    asm("v_cvt_pk_bf16_f32 %0, %1, %2" : "=v"(r.u[3]) : "v"(b.z), "v"(b.w));
    return r.v;
}

// Pack [W_ih | W_hh] into exact MFMA B-fragment order, bf16, gate-interleaved
// columns (packed col n = 4*j_hidden + gate):
// Wpk[(((c*48 + kc)*64 + lane))*8 + j] = W[row(n)][k], n = c*16 + (lane&15),
// k = kc*32 + (lane>>4)*8 + j.
__global__ __launch_bounds__(256) void pack_w(const float* __restrict__ W_ih,
                                              const float* __restrict__ W_hh,
                                              unsigned short* __restrict__ Wpk) {
    int tid = blockIdx.x * 256 + threadIdx.x;        // [0, 256*48*64*8)
    int j    = tid & 7;
    int lane = (tid >> 3) & 63;
    int rest = tid >> 9;
    int kc = rest % KC_N;
    int c  = rest / KC_N;
    int npk = c * 16 + (lane & 15);
    int jh = npk >> 2, g = npk & 3;
    int row = g * H_ + jh;                           // torch gate order i,f,g,o
    int k = kc * 32 + (lane >> 4) * 8 + j;
    float v = (k < D_) ? W_ih[row * D_ + k] : W_hh[row * H_ + (k - D_)];
    Wpk[tid] = f2bf(v);
}

__global__ __launch_bounds__(256) void init_state2(
    const float* __restrict__ h0, const float* __restrict__ b_ih,
    const float* __restrict__ b_hh, unsigned short* __restrict__ hbuf,
    float* __restrict__ bias_p, unsigned int* __restrict__ flags)
{
    int tid = blockIdx.x * 256 + threadIdx.x;        // 65536 threads
    int j = tid & (H_ - 1);
    hbuf[tid] = f2bf(h0[j]);                         // h buffer 0: [64][1024] bf16
    if (tid < G4) {                                  // bias in packed-col order
        int jh = tid >> 2, g = tid & 3;
        bias_p[tid] = b_ih[g * H_ + jh] + b_hh[g * H_ + jh];
    }
    if (tid < 256) flags[tid] = 0u;                  // per-block step counters
}

// Persistent LSTM: 256 blocks (1/CU), 512 threads (8 waves).
// block = (colgroup cg: 32 packed cols = 8 hidden units) x (batch half mh: 32 rows)
// wave  = (mi: 16-row m-tile) x (ks: k-slice of 4 x-kc + 8 h-kc)
// Weights pinned in VGPRs: plain loads + empty-asm "+v" keep-alive (rule-17
// liveness pin -> cannot be rematerialized or sunk into the t-loop).
// Barrier: RMW-free — arrival = plain sc1 store to own flag; detect = wave0
// loads all 128 flags in one dwordx2/lane + __all ballot. x-MFMAs overlap wait.
__global__ __launch_bounds__(512) void lstm_persist(
    const float* __restrict__ x, const int* __restrict__ mask,
    const unsigned short* __restrict__ Wpk, const float* __restrict__ bias_p,
    const float* __restrict__ h0, const float* __restrict__ c0,
    unsigned short* __restrict__ hbuf, float* __restrict__ out,
    unsigned int* __restrict__ flags)
{
    const int tid = threadIdx.x;
    const int bid = blockIdx.x;
    const int cg  = bid >> 1;            // 0..127 colgroup
    const int mh  = bid & 1;             // batch half
    const int b0g = mh << 5;

    const int w = tid >> 6, l = tid & 63;
    const int quad = l >> 4, l15 = l & 15;
    const int mi = w >> 2;               // 0..1
    const int ks = w & 3;                // 0..3
    const int arow = b0g + mi * 16 + l15;

    __shared__ float Dls[4][32][36];     // [ks][m-row][gate-col], padded

    // ---- pinned B fragments: wave's 12 kc = {ks*4+0..3 (x), 16+ks*8+0..7 (h)} ----
    s16x8 Bf0[12], Bf1[12];
    {
        const unsigned short* base0 = Wpk + (size_t)((cg * 2 + 0) * KC_N) * 512;
        const unsigned short* base1 = Wpk + (size_t)((cg * 2 + 1) * KC_N) * 512;
        #pragma unroll
        for (int i = 0; i < 12; ++i) {
            int kc = (i < 4) ? (ks * 4 + i) : (16 + ks * 8 + (i - 4));
            Bf0[i] = *reinterpret_cast<const s16x8*>(base0 + ((size_t)kc * 64 + l) * 8);
            Bf1[i] = *reinterpret_cast<const s16x8*>(base1 + ((size_t)kc * 64 + l) * 8);
        }
        // liveness pin: values become opaque -> must stay resident in VGPRs
        #pragma unroll
        for (int i = 0; i < 12; ++i)
            asm volatile("" : "+v"(Bf0[i]), "+v"(Bf1[i]));
    }

    // ---- epilogue thread state (tid<256): thread -> (batch b_l, hidden unit u) ----
    const int b_l = tid >> 3, u = tid & 7;
    const int brow = b0g + b_l;
    const int jcol = cg * 8 + u;
    float c_reg = 0.f, h_reg = 0.f;
    float4 bias = make_float4(0.f, 0.f, 0.f, 0.f);
    if (tid < 256) {
        c_reg = c0[jcol];
        h_reg = h0[jcol];
        bias = *reinterpret_cast<const float4*>(bias_p + cg * 32 + u * 4);
    }

    unsigned int* myflag = flags + mh * 128 + cg;
    const unsigned long long* pollp =
        reinterpret_cast<const unsigned long long*>(flags + mh * 128) + l;
    const float* xbase = x + (size_t)arow * T_ * D_ + ks * 128 + quad * 8;

    #pragma unroll 1
    for (int t = 0; t < T_; ++t) {
        const unsigned short* hin  = hbuf + (size_t)(t & 1) * (B_ * H_);
        unsigned short*       hout = hbuf + (size_t)((t + 1) & 1) * (B_ * H_);

        // ---- phase A: x-part MFMA (no h dependency) + mask prefetch ----
        f32x4 a0 = {0.f, 0.f, 0.f, 0.f}, a1 = {0.f, 0.f, 0.f, 0.f};
        const float* xp = xbase + (size_t)t * D_;
        int mv = 0;
        if (tid < 256) mv = mask[(size_t)brow * T_ + t];
        #pragma unroll
        for (int i = 0; i < 4; ++i) {
            float4 v0 = *reinterpret_cast<const float4*>(xp + i * 32);
            float4 v1 = *reinterpret_cast<const float4*>(xp + i * 32 + 4);
            s16x8 af = cvt8(v0, v1);
            a0 = __builtin_amdgcn_mfma_f32_16x16x32_bf16(af, Bf0[i], a0, 0, 0, 0);
            a1 = __builtin_amdgcn_mfma_f32_16x16x32_bf16(af, Bf1[i], a1, 0, 0, 0);
        }

        // ---- barrier wait: wave 0 polls all 128 flags of its half (no RMW) ----
        if (t > 0 && w == 0) {
            const unsigned int tgt = (unsigned int)t;
            int guard = 0;
            for (;;) {
                unsigned long long v = __hip_atomic_load(pollp, __ATOMIC_RELAXED,
                                                         __HIP_MEMORY_SCOPE_AGENT);
                int ok = ((unsigned int)v >= tgt) && ((unsigned int)(v >> 32) >= tgt);
                if (__all(ok)) break;
                __builtin_amdgcn_s_sleep(2);
                if (++guard > (1 << 16)) break;   // hard bail: wrong-answer, never hang
            }
        }
        __builtin_amdgcn_s_barrier();                              // raw: no vmcnt drain
        __builtin_amdgcn_fence(__ATOMIC_ACQUIRE, "workgroup");     // compiler ordering

        // ---- phase B: h-part — issue ALL 16 coherent loads, then MFMA chain ----
        const unsigned short* hrow = hin + (size_t)arow * H_ + ks * 256 + quad * 8;
        s16x8 hf[8];
        #pragma unroll
        for (int i = 0; i < 8; ++i) {
            const unsigned long long* hp =
                reinterpret_cast<const unsigned long long*>(hrow + i * 32);
            union { s16x8 v; unsigned long long q[2]; } au;
            au.q[0] = __hip_atomic_load(hp,     __ATOMIC_RELAXED, __HIP_MEMORY_SCOPE_AGENT);
            au.q[1] = __hip_atomic_load(hp + 1, __ATOMIC_RELAXED, __HIP_MEMORY_SCOPE_AGENT);
            hf[i] = au.v;
        }
        #pragma unroll
        for (int i = 0; i < 8; ++i) {
            a0 = __builtin_amdgcn_mfma_f32_16x16x32_bf16(hf[i], Bf0[4 + i], a0, 0, 0, 0);
            a1 = __builtin_amdgcn_mfma_f32_16x16x32_bf16(hf[i], Bf1[4 + i], a1, 0, 0, 0);
        }
        // C/D layout: col = lane&15, row = quad*4 + reg (m89-verified)
        #pragma unroll
        for (int r = 0; r < 4; ++r) {
            Dls[ks][mi * 16 + quad * 4 + r][l15]      = a0[r];
            Dls[ks][mi * 16 + quad * 4 + r][16 + l15] = a1[r];
        }
        __syncthreads();

        // ---- epilogue: reduce 4 k-slices, LSTM cell, h store (sc1) ----
        float h2s = 0.f;
        if (tid < 256) {
            f32x4 s0 = *reinterpret_cast<f32x4*>(&Dls[0][b_l][u * 4]);
            f32x4 s1 = *reinterpret_cast<f32x4*>(&Dls[1][b_l][u * 4]);
            f32x4 s2 = *reinterpret_cast<f32x4*>(&Dls[2][b_l][u * 4]);
            f32x4 s3 = *reinterpret_cast<f32x4*>(&Dls[3][b_l][u * 4]);
            f32x4 g = s0 + s1 + s2 + s3;
            float gi = sigm  (g[0] + bias.x);
            float gf = sigm  (g[1] + bias.y);
            float gg = tanh_f(g[2] + bias.z);
            float go = sigm  (g[3] + bias.w);
            float c_new = gf * c_reg + gi * gg;
            float h_new = go * tanh_f(c_new);
            float h2 = mv ? h_new : h_reg;
            c_reg = mv ? c_new : c_reg;
            h_reg = h2;
            h2s = h2;
            // pair adjacent units into one dword, store coherently (sc1)
            unsigned int hv = (unsigned int)f2bf(h2);
            unsigned int hx = (unsigned int)__shfl_xor((int)hv, 1);
            if ((u & 1) == 0) {
                unsigned int pk = (hx << 16) | hv;
                __hip_atomic_store(reinterpret_cast<unsigned int*>(
                                       hout + (size_t)brow * H_ + jcol),
                                   pk, __ATOMIC_RELAXED, __HIP_MEMORY_SCOPE_AGENT);
            }
        }
        __syncthreads();   // drains vmcnt per wave: h stores visible before arrival

        // ---- arrival: one plain sc1 store; out[] store moved off critical path ----
        if (t < T_ - 1 && tid == 0)
            __hip_atomic_store(myflag, (unsigned int)(t + 1),
                               __ATOMIC_RELAXED, __HIP_MEMORY_SCOPE_AGENT);
        if (tid < 256)
            out[((size_t)brow * T_ + t) * H_ + jcol] = h2s;
    }
}

extern "C" void kernel_launch(void* const* d_in, const int* in_sizes, int n_in,
                              void* d_out, int out_size, void* d_ws, size_t ws_size,
                              hipStream_t stream)
{
    const float* x    = (const float*)d_in[0];
    const int*   mask = (const int*)d_in[1];
    const float* W_ih = (const float*)d_in[2];
    const float* W_hh = (const float*)d_in[3];
    const float* b_ih = (const float*)d_in[4];
    const float* b_hh = (const float*)d_in[5];
    const float* h0   = (const float*)d_in[6];
    const float* c0   = (const float*)d_in[7];
    float* out = (float*)d_out;

    // ws layout (~12.9 MB total)
    char* wsb = (char*)d_ws;
    unsigned short* Wpk    = (unsigned short*)(wsb);             // 12,582,912 B
    float*          bias_p = (float*)(wsb + 12582912);           //     16,384 B
    unsigned short* hbuf   = (unsigned short*)(wsb + 12599296);  //    262,144 B (2 buffers)
    unsigned int*   flags  = (unsigned int*)(wsb + 12861440);    //      1,024 B

    // inputs re-poisoned every call -> re-pack every call
    pack_w<<<24576, 256, 0, stream>>>(W_ih, W_hh, Wpk);
    init_state2<<<256, 256, 0, stream>>>(h0, b_ih, b_hh, hbuf, bias_p, flags);
    lstm_persist<<<256, 512, 0, stream>>>(x, mask, Wpk, bias_p, h0, c0, hbuf, out, flags);
}